// Round 3
// baseline (954.872 us; speedup 1.0000x reference)
//
#include <hip/hip_runtime.h>

#define N_TOK 32768
#define N_EMB 4096
#define DIM 256

typedef short bf16x8 __attribute__((ext_vector_type(8)));
typedef float f32x4 __attribute__((ext_vector_type(4)));
typedef unsigned short us8 __attribute__((ext_vector_type(8)));

// ---------------- ws layout (primary, ws_size >= 20 MB) ----------------
// [0, 16384)        counts    uint[4096]
// [16384, 16388)    loss_acc  float
// [16896, 33280)    e2_np     float[4096]
// [33280, 164352)   x2_np     float[32768]
// [1 MB, 17 MB)     Xh        bf16[32768*256] MFMA-shuffled
// [17 MB, 19 MB)    Wh        bf16[4096*256]  MFMA-shuffled
// Fallback (small ws): Xh/Wh in encodings region + separate k_onehot (r8 path).

static __device__ __forceinline__ unsigned short f2bf(float f) {
    unsigned int u = __float_as_uint(f);
    u = (u + 0x7fffu + ((u >> 16) & 1u)) >> 16;   // RTN-even
    return (unsigned short)u;
}

// pack 6-bit id into low mantissa bits (<=64 ulp perturbation << 1.5e-4 margin)
static __device__ __forceinline__ float pkid(float x, unsigned int id) {
    return __uint_as_float((__float_as_uint(x) & ~63u) | id);
}

// ---------------- numpy-pairwise fp32 row norms (r3-proven bit-exact) ------
__device__ __forceinline__ float pw128_sq(const float4* a4) {
#pragma clang fp contract(off)
    float4 v0 = a4[0], v1 = a4[1];
    float r0 = v0.x * v0.x, r1 = v0.y * v0.y, r2 = v0.z * v0.z, r3 = v0.w * v0.w;
    float r4 = v1.x * v1.x, r5 = v1.y * v1.y, r6 = v1.z * v1.z, r7 = v1.w * v1.w;
    #pragma unroll
    for (int i = 1; i < 16; ++i) {
        v0 = a4[2 * i]; v1 = a4[2 * i + 1];
        float s;
        s = v0.x * v0.x; r0 += s;
        s = v0.y * v0.y; r1 += s;
        s = v0.z * v0.z; r2 += s;
        s = v0.w * v0.w; r3 += s;
        s = v1.x * v1.x; r4 += s;
        s = v1.y * v1.y; r5 += s;
        s = v1.z * v1.z; r6 += s;
        s = v1.w * v1.w; r7 += s;
    }
    return ((r0 + r1) + (r2 + r3)) + ((r4 + r5) + (r6 + r7));
}

__global__ __launch_bounds__(256) void k_norm_np(const float* __restrict__ src,
                                                 float* __restrict__ dst, int nrows) {
#pragma clang fp contract(off)
    int row = blockIdx.x * 256 + threadIdx.x;
    if (row >= nrows) return;
    const float4* a = (const float4*)(src + (size_t)row * DIM);
    float lo = pw128_sq(a);
    float hi = pw128_sq(a + 32);
    dst[row] = lo + hi;
}

// ---------------- bf16 cast + MFMA-fragment shuffle ----------------
__global__ __launch_bounds__(256) void k_shuf1(const float* __restrict__ src,
                                               unsigned short* __restrict__ hi) {
    int tid = blockIdx.x * 256 + threadIdx.x;
    int b = tid >> 6, lane = tid & 63;
    int T = b >> 3, C = b & 7;
    int row = T * 16 + (lane & 15);
    int col = C * 32 + (lane >> 4) * 8;
    const float* s = src + (size_t)row * DIM + col;
    us8 h;
    #pragma unroll
    for (int j = 0; j < 8; ++j) h[j] = f2bf(s[j]);
    *(us8*)(hi + (size_t)tid * 8) = h;
}

// ---- fused MFMA scoring: 64 tokens/block, single pass, packed top-2 ----
// vs r2: the enc zero-drip is REMOVED from the jt loop (it shared the vmcnt
// FIFO with the bh loads -> every waitcnt before MFMA drained HBM stores,
// serializing the loop; rocprof: 45% BW / 7% Mfma / 7% VALU). enc zeroing is
// now a separate hipMemsetAsync dispatch (~6.3 TB/s); score keeps only the
// 1.0f scatter (ordering via dispatch boundary). Wh stays L2-resident.
__global__ __launch_bounds__(256, 3) void k_score_mfma(
        const float* __restrict__ x, const float* __restrict__ w,
        const float* __restrict__ e2_np, const float* __restrict__ x2_np,
        const unsigned short* __restrict__ Xh,
        const unsigned short* __restrict__ Wh,
        float* __restrict__ out_idx, unsigned int* __restrict__ counts,
        float* enc,                       // nullable: fused 1.0f scatter
        float* __restrict__ outq, float* __restrict__ loss_acc) {
    __shared__ __align__(16) short Abuf[16384];  // [tile(4)][C(8)][lane][8] = 32 KB
    __shared__ float Tmax[4][64];
    __shared__ unsigned int ccnt[64];
    __shared__ int clist[64][16];
    __shared__ float Red_d[64 * 4];
    __shared__ int   Red_i[64 * 4];
    __shared__ float sred[4];

    const int t = threadIdx.x;
    const int wave = t >> 6, lane = t & 63;
    const int tok0 = blockIdx.x * 64;
    const int q = lane >> 4, c = lane & 15;

    // ---- stage A (4 tiles x 8 chunks x 1KB = 32 KB) ----
    #pragma unroll
    for (int i = 0; i < 8; ++i) {
        int idx = wave * 8 + i;             // 0..31
        int tile = idx >> 3, C = idx & 7;
        int Tg = blockIdx.x * 4 + tile;
        const unsigned short* src = Xh + ((size_t)(Tg * 8 + C) * 64 + lane) * 8;
        __builtin_amdgcn_global_load_lds(
            (const __attribute__((address_space(1))) unsigned int*)src,
            (__attribute__((address_space(3))) unsigned int*)(Abuf + idx * 512),
            16, 0, 0);
    }
    if (t < 64) ccnt[t] = 0;
    __syncthreads();

    // ---- single pass: per-token packed top-2 (pure MFMA + loads) ----
    float vmax[16], v2[16];
    #pragma unroll
    for (int s = 0; s < 16; ++s) { vmax[s] = -3.4e38f; v2[s] = -3.4e38f; }
    for (int jt = 0; jt < N_EMB; jt += 256) {
        const int U0 = (jt >> 4) + wave * 4;
        f32x4 acc[4][4] = {};
        #pragma unroll
        for (int C = 0; C < 8; ++C) {
            bf16x8 ah[4];
            #pragma unroll
            for (int m = 0; m < 4; ++m)
                ah[m] = *(const bf16x8*)(Abuf + (size_t)(m * 8 + C) * 512 + lane * 8);
            #pragma unroll
            for (int n = 0; n < 4; ++n) {
                bf16x8 bh = *(const bf16x8*)(Wh + (((size_t)(U0 + n) * 8 + C) * 64 + lane) * 8);
                #pragma unroll
                for (int m = 0; m < 4; ++m)
                    acc[m][n] = __builtin_amdgcn_mfma_f32_16x16x32_bf16(ah[m], bh, acc[m][n], 0, 0, 0);
            }
        }
        // packed top-2 update via exact max3/med3 tournament
        {
            unsigned int idb = ((unsigned int)jt >> 8) << 2;
            #pragma unroll
            for (int m = 0; m < 4; ++m)
                #pragma unroll
                for (int r = 0; r < 4; ++r) {
                    int s = m * 4 + r;
                    float p0 = pkid(acc[m][0][r], idb + 0);
                    float p1 = pkid(acc[m][1][r], idb + 1);
                    float p2 = pkid(acc[m][2][r], idb + 2);
                    float p3 = pkid(acc[m][3][r], idb + 3);
                    float t1a = fmaxf(fmaxf(vmax[s], p0), p1);
                    float t2a = __builtin_amdgcn_fmed3f(vmax[s], p0, p1);
                    float t1b = fmaxf(fmaxf(v2[s], p2), p3);
                    float t2b = __builtin_amdgcn_fmed3f(v2[s], p2, p3);
                    vmax[s] = fmaxf(t1a, t1b);
                    v2[s]   = fmaxf(fmaxf(fminf(t1a, t1b), t2a), t2b);
                }
        }
    }
    // reduce over the 16 c-lanes of each q-group (keep per-thread vmax/v2!)
    float rmax[16];
    #pragma unroll
    for (int s = 0; s < 16; ++s) rmax[s] = vmax[s];
    #pragma unroll
    for (int off = 1; off < 16; off <<= 1)
        #pragma unroll
        for (int s = 0; s < 16; ++s)
            rmax[s] = fmaxf(rmax[s], __shfl_xor(rmax[s], off));
    if (c == 0) {
        #pragma unroll
        for (int m = 0; m < 4; ++m)
            #pragma unroll
            for (int r = 0; r < 4; ++r)
                Tmax[wave][m * 16 + q * 4 + r] = rmax[m * 4 + r];
    }
    __syncthreads();
    if (t < 64) {
        float mx = fmaxf(fmaxf(Tmax[0][t], Tmax[1][t]),
                         fmaxf(Tmax[2][t], Tmax[3][t]));
        Tmax[0][t] = mx - 1.5e-4f;     // threshold (r6/r7-proven margin)
    }
    __syncthreads();
    float thr[16];
    #pragma unroll
    for (int m = 0; m < 4; ++m)
        #pragma unroll
        for (int r = 0; r < 4; ++r)
            thr[m * 4 + r] = Tmax[0][m * 16 + q * 4 + r];

    // ---- candidate push from registers (no recompute pass) ----
    #pragma unroll
    for (int s = 0; s < 16; ++s) {
        int m = s >> 2, r = s & 3;
        int tokl = m * 16 + q * 4 + r;
        #pragma unroll
        for (int h = 0; h < 2; ++h) {
            float pv = h ? v2[s] : vmax[s];
            if (pv >= thr[s]) {
                unsigned int id = __float_as_uint(pv) & 63u;
                int code = ((int)(id >> 2) * 16 + wave * 4 + (int)(id & 3u)) * 16 + c;
                unsigned int p = atomicAdd(&ccnt[tokl], 1u);
                if (p < 16) clist[tokl][p] = code;
            }
        }
    }
    __syncthreads();

    // ---- np-fp32-exact refinement: 4 threads/token over the list ----
    {
        int token = t >> 2, slot = t & 3;
        int cnt = (int)ccnt[token]; if (cnt > 16) cnt = 16;
        float bd = 3.4e38f;
        int bi = 0x7fffffff;
        float x2 = x2_np[tok0 + token];
        const float4* xr = (const float4*)(x + (size_t)(tok0 + token) * DIM);
        for (int k = slot; k < cnt; k += 4) {
            int code = clist[token][k];
            const float4* wr = (const float4*)(w + (size_t)code * DIM);
            double dot = 0.0;
            for (int g = 0; g < 64; ++g) {
                float4 xv = xr[g];
                float4 wv = wr[g];
                dot += (double)xv.x * (double)wv.x;
                dot += (double)xv.y * (double)wv.y;
                dot += (double)xv.z * (double)wv.z;
                dot += (double)xv.w * (double)wv.w;
            }
            {
#pragma clang fp contract(off)
                float M  = (float)dot;          // BLAS sgemm entry (~2e-9)
                float S  = x2 + e2_np[code];    // np broadcast add (fp32)
                float dd = S - 2.0f * M;        // fp32 sub -> ulp bucket
                if (dd < bd || (dd == bd && code < bi)) { bd = dd; bi = code; }
            }
        }
        Red_d[token * 4 + slot] = bd;
        Red_i[token * 4 + slot] = bi;
    }
    __syncthreads();
    if (t < 64) {
        float fv = Red_d[t * 4];
        int   fi = Red_i[t * 4];
        #pragma unroll
        for (int k = 1; k < 4; ++k) {
            float v = Red_d[t * 4 + k];
            int  ii = Red_i[t * 4 + k];
            if (v < fv || (v == fv && ii < fi)) { fv = v; fi = ii; }
        }
        out_idx[tok0 + t] = (float)fi;
        atomicAdd(&counts[fi], 1u);
        ccnt[t] = (unsigned int)fi;   // publish for epilogue
    }
    __syncthreads();

    // ---- epilogue: 1.0f scatter + quantized gather + commitment loss ----
    {
        int token = t >> 2, slot = t & 3;
        int fi = (int)ccnt[token];
        // enc rows were zeroed by the preceding memset dispatch; dispatch
        // boundary orders it before this scatter.
        if (enc && slot == 0)
            __builtin_nontemporal_store(1.0f, enc + (size_t)(tok0 + token) * N_EMB + fi);
        const f32x4* wr = (const f32x4*)(w + (size_t)fi * DIM);
        const f32x4* xr = (const f32x4*)(x + (size_t)(tok0 + token) * DIM);
        f32x4* oq = (f32x4*)(outq + (size_t)(tok0 + token) * DIM);
        float sse = 0.f;
        #pragma unroll
        for (int g0 = 0; g0 < 16; ++g0) {
            int g = slot * 16 + g0;
            f32x4 qv = wr[g];
            f32x4 xv = xr[g];
            __builtin_nontemporal_store(qv, oq + g);
            float dx = qv.x - xv.x, dy = qv.y - xv.y;
            float dz = qv.z - xv.z, dw = qv.w - xv.w;
            sse += dx * dx + dy * dy + dz * dz + dw * dw;
        }
        #pragma unroll
        for (int off = 32; off > 0; off >>= 1) sse += __shfl_down(sse, off, 64);
        if (lane == 0) sred[wave] = sse;
    }
    __syncthreads();
    if (t == 0)
        atomicAdd(loss_acc, sred[0] + sred[1] + sred[2] + sred[3]);
}

// ---------------- one-hot encodings (fallback path only) ----------------
__global__ __launch_bounds__(256) void k_onehot(const float* __restrict__ out_idx,
                                                float* __restrict__ enc) {
    int token = blockIdx.x;
    int idx = (int)out_idx[token];
    float4* row = (float4*)(enc + (size_t)token * N_EMB);
    #pragma unroll
    for (int p = 0; p < 4; ++p) {
        int g = threadIdx.x + 256 * p;
        float4 v = make_float4(0.f, 0.f, 0.f, 0.f);
        int d0 = g * 4;
        if (idx >= d0 && idx < d0 + 4) ((float*)&v)[idx - d0] = 1.0f;
        row[g] = v;
    }
}

// ---------------- perplexity + loss finalize ----------------
__global__ __launch_bounds__(256) void k_final(const unsigned int* __restrict__ counts,
                                               const float* __restrict__ loss_acc,
                                               float* __restrict__ out_perp,
                                               float* __restrict__ out_loss) {
    __shared__ float sred[4];
    int t = threadIdx.x;
    float h = 0.f;
    for (int k = t; k < N_EMB; k += 256) {
        float p = (float)counts[k] * (1.0f / N_TOK);
        h += p * logf(p + 1e-10f);
    }
    #pragma unroll
    for (int off = 32; off > 0; off >>= 1) h += __shfl_down(h, off, 64);
    if ((t & 63) == 0) sred[t >> 6] = h;
    __syncthreads();
    if (t == 0) {
        float s = sred[0] + sred[1] + sred[2] + sred[3];
        *out_perp = expf(-s);
        *out_loss = loss_acc[0] * 1.25f / 8388608.0f;
    }
}

extern "C" void kernel_launch(void* const* d_in, const int* in_sizes, int n_in,
                              void* d_out, int out_size, void* d_ws, size_t ws_size,
                              hipStream_t stream) {
    const float* x = (const float*)d_in[0];
    const float* w = (const float*)d_in[1];
    float* out  = (float*)d_out;
    float* out0 = out;                       // quantized_st [32768*256]
    float* out1 = out0 + 8388608;            // perplexity   [1]
    float* out2 = out1 + 1;                  // encodings    [32768*4096]
    float* out3 = out2 + 134217728;          // indices      [32768] (as float)
    float* out4 = out3 + 32768;              // loss         [1]

    unsigned int* counts = (unsigned int*)d_ws;
    float* loss_acc = (float*)((char*)d_ws + 16384);
    float* e2_np    = (float*)((char*)d_ws + 16896);
    float* x2_np    = (float*)((char*)d_ws + 33280);

    // Primary: scratch in d_ws, enc zeroed via dedicated memset dispatch and
    // 1.0f scattered in k_score. Fallback (small ws): Xh/Wh alias out2 so no
    // memset is possible -> full-row k_onehot after score.
    bool big_ws = ws_size >= (size_t)(20u * 1024u * 1024u);
    unsigned short *Xh, *Wh;
    float* enc_arg;
    if (big_ws) {
        Xh = (unsigned short*)((char*)d_ws + (1u << 20));   // 16 MB
        Wh = Xh + 8388608;                                   // 2 MB
        enc_arg = out2;
    } else {
        uintptr_t sb = ((uintptr_t)out2 + 255) & ~(uintptr_t)255;
        Xh = (unsigned short*)sb;
        Wh = Xh + 8388608;
        enc_arg = nullptr;
    }

    hipMemsetAsync(d_ws, 0, 16640, stream);
    k_norm_np<<<N_EMB / 256, 256, 0, stream>>>(w, e2_np, N_EMB);
    k_norm_np<<<N_TOK / 256, 256, 0, stream>>>(x, x2_np, N_TOK);
    k_shuf1<<<N_TOK * DIM / 8 / 256, 256, 0, stream>>>(x, Xh);
    k_shuf1<<<N_EMB * DIM / 8 / 256, 256, 0, stream>>>(w, Wh);
    if (big_ws)
        hipMemsetAsync(out2, 0, (size_t)N_TOK * N_EMB * sizeof(float), stream);
    k_score_mfma<<<N_TOK / 64, 256, 0, stream>>>(x, w, e2_np, x2_np, Xh, Wh,
                                                 out3, counts, enc_arg,
                                                 out0, loss_acc);
    if (!big_ws)
        k_onehot<<<N_TOK, 256, 0, stream>>>(out3, out2);
    k_final<<<1, 256, 0, stream>>>(counts, loss_acc, out1, out4);
}

// Round 4
// 813.385 us; speedup vs baseline: 1.1739x; 1.1739x over previous
//
#include <hip/hip_runtime.h>

#define N_TOK 32768
#define N_EMB 4096
#define DIM 256
#define MARGIN 2.5e-4f

typedef short bf16x8 __attribute__((ext_vector_type(8)));
typedef float f32x4 __attribute__((ext_vector_type(4)));
typedef float f32x2 __attribute__((ext_vector_type(2)));
typedef unsigned short us8 __attribute__((ext_vector_type(8)));

// ---------------- ws layout (primary, ws_size >= 24 MB) ----------------
// [0, 16384)        counts    uint[4096]
// [16384, 16388)    loss_acc  float
// [16896, 33280)    e2_np     float[4096]
// [33280, 164352)   x2_np     float[32768]
// [1 MB, 17 MB)     Xh        bf16[32768*256] MFMA-shuffled
// [17 MB, 19 MB)    Wh        bf16[4096*256]  MFMA-shuffled
// [19 MB, 23 MB)    pairs     float2[32768*16] per-(token,ntile) top-2
// Fallback (small ws): Xh/Wh/pairs in encodings region + k_onehot.

static __device__ __forceinline__ unsigned short f2bf(float f) {
    unsigned int u = __float_as_uint(f);
    u = (u + 0x7fffu + ((u >> 16) & 1u)) >> 16;   // RTN-even
    return (unsigned short)u;
}

// pack 12-bit global code id into low mantissa (<=4096 ulp ~ 3e-5 at |M|<=0.1,
// covered by MARGIN 2.5e-4 vs proven 1.5e-4 + 64-ulp config)
static __device__ __forceinline__ float pk12(float x, unsigned int id) {
    return __uint_as_float((__float_as_uint(x) & ~4095u) | id);
}

// ---------------- numpy-pairwise fp32 row norms (r3-proven bit-exact) ------
__device__ __forceinline__ float pw128_sq(const float4* a4) {
#pragma clang fp contract(off)
    float4 v0 = a4[0], v1 = a4[1];
    float r0 = v0.x * v0.x, r1 = v0.y * v0.y, r2 = v0.z * v0.z, r3 = v0.w * v0.w;
    float r4 = v1.x * v1.x, r5 = v1.y * v1.y, r6 = v1.z * v1.z, r7 = v1.w * v1.w;
    #pragma unroll
    for (int i = 1; i < 16; ++i) {
        v0 = a4[2 * i]; v1 = a4[2 * i + 1];
        float s;
        s = v0.x * v0.x; r0 += s;
        s = v0.y * v0.y; r1 += s;
        s = v0.z * v0.z; r2 += s;
        s = v0.w * v0.w; r3 += s;
        s = v1.x * v1.x; r4 += s;
        s = v1.y * v1.y; r5 += s;
        s = v1.z * v1.z; r6 += s;
        s = v1.w * v1.w; r7 += s;
    }
    return ((r0 + r1) + (r2 + r3)) + ((r4 + r5) + (r6 + r7));
}

__global__ __launch_bounds__(256) void k_norm_np(const float* __restrict__ src,
                                                 float* __restrict__ dst, int nrows) {
#pragma clang fp contract(off)
    int row = blockIdx.x * 256 + threadIdx.x;
    if (row >= nrows) return;
    const float4* a = (const float4*)(src + (size_t)row * DIM);
    float lo = pw128_sq(a);
    float hi = pw128_sq(a + 32);
    dst[row] = lo + hi;
}

// ---------------- bf16 cast + MFMA-fragment shuffle ----------------
__global__ __launch_bounds__(256) void k_shuf1(const float* __restrict__ src,
                                               unsigned short* __restrict__ hi) {
    int tid = blockIdx.x * 256 + threadIdx.x;
    int b = tid >> 6, lane = tid & 63;
    int T = b >> 3, C = b & 7;
    int row = T * 16 + (lane & 15);
    int col = C * 32 + (lane >> 4) * 8;
    const float* s = src + (size_t)row * DIM + col;
    us8 h;
    #pragma unroll
    for (int j = 0; j < 8; ++j) h[j] = f2bf(s[j]);
    *(us8*)(hi + (size_t)tid * 8) = h;
}

// ---- k_top2: GEMM-tiled scoring. 8192 blocks = 512 mtiles x 16 ntiles. ----
// Each block: 64 tokens x 256 codes, single K=256 sweep (R3's proven MFMA
// body minus the jt loop). Emits per-(token,ntile) exact top-2 packed pairs.
// Rationale (r3 counters): monolithic 512-block version was latency-bound
// (7% pipes, 22% occ) and re-fetched Wh from HBM (465 MB). Here: 32 blocks/CU
// queued; Wh tile reused by 512 blocks via L2. enc zero-fill fused as
// post-compute NT stores (64 KB/block) -> replaces the 85us serial memset.
__global__ __launch_bounds__(256, 4) void k_top2(
        const unsigned short* __restrict__ Xh,
        const unsigned short* __restrict__ Wh,
        f32x2* __restrict__ pairs, float* enc) {
    __shared__ __align__(16) short Abuf[16384];  // [tile(4)][C(8)][lane][8] = 32 KB
    __shared__ float M1[4][64], M2[4][64];

    const int t = threadIdx.x;
    const int wave = t >> 6, lane = t & 63;
    const int q = lane >> 4, c = lane & 15;
    const int bid = blockIdx.x;
    const int mtile = bid >> 4, ntile = bid & 15;
    const int tok0 = mtile * 64;

    // ---- stage A-tile (4 T x 8 C x 1KB = 32 KB) ----
    #pragma unroll
    for (int i = 0; i < 8; ++i) {
        int idx = wave * 8 + i;             // 0..31
        int tile = idx >> 3, C = idx & 7;
        const unsigned short* src = Xh + ((size_t)((mtile * 4 + tile) * 8 + C) * 64 + lane) * 8;
        __builtin_amdgcn_global_load_lds(
            (const __attribute__((address_space(1))) unsigned int*)src,
            (__attribute__((address_space(3))) unsigned int*)(Abuf + idx * 512),
            16, 0, 0);
    }
    __syncthreads();

    // ---- MFMA: 64 tok x 256 codes, K=256 ----
    const int U0 = ntile * 16 + wave * 4;
    f32x4 acc[4][4] = {};
    #pragma unroll
    for (int C = 0; C < 8; ++C) {
        bf16x8 ah[4];
        #pragma unroll
        for (int m = 0; m < 4; ++m)
            ah[m] = *(const bf16x8*)(Abuf + (size_t)(m * 8 + C) * 512 + lane * 8);
        #pragma unroll
        for (int n = 0; n < 4; ++n) {
            bf16x8 bh = *(const bf16x8*)(Wh + (((size_t)(U0 + n) * 8 + C) * 64 + lane) * 8);
            #pragma unroll
            for (int m = 0; m < 4; ++m)
                acc[m][n] = __builtin_amdgcn_mfma_f32_16x16x32_bf16(ah[m], bh, acc[m][n], 0, 0, 0);
        }
    }

    // ---- per-thread exact top-2 over its 4 codes (12-bit id packed) ----
    float v1[16], v2[16];
    #pragma unroll
    for (int m = 0; m < 4; ++m)
        #pragma unroll
        for (int r = 0; r < 4; ++r) {
            int s = m * 4 + r;
            float p0 = pk12(acc[m][0][r], (unsigned)((U0 + 0) * 16 + c));
            float p1 = pk12(acc[m][1][r], (unsigned)((U0 + 1) * 16 + c));
            float p2 = pk12(acc[m][2][r], (unsigned)((U0 + 2) * 16 + c));
            float p3 = pk12(acc[m][3][r], (unsigned)((U0 + 3) * 16 + c));
            float t1a = fmaxf(p0, p1), t2a = fminf(p0, p1);
            float t1b = fmaxf(p2, p3), t2b = fminf(p2, p3);
            v1[s] = fmaxf(t1a, t1b);
            v2[s] = fmaxf(fminf(t1a, t1b), (t1a >= t1b) ? t2a : t2b);
        }
    // butterfly top-2 merge over the 16 c-lanes
    #pragma unroll
    for (int off = 1; off < 16; off <<= 1)
        #pragma unroll
        for (int s = 0; s < 16; ++s) {
            float o1 = __shfl_xor(v1[s], off);
            float o2 = __shfl_xor(v2[s], off);
            float big = fmaxf(v1[s], o1);
            v2[s] = fmaxf(fminf(v1[s], o1), (v1[s] >= o1) ? v2[s] : o2);
            v1[s] = big;
        }
    if (c == 0) {
        #pragma unroll
        for (int m = 0; m < 4; ++m)
            #pragma unroll
            for (int r = 0; r < 4; ++r) {
                int tokl = m * 16 + q * 4 + r;
                M1[wave][tokl] = v1[m * 4 + r];
                M2[wave][tokl] = v2[m * 4 + r];
            }
    }
    __syncthreads();

    // ---- fused enc zero-fill: this block zeroes enc[bid*16384 .. +16384) ----
    if (enc) {
        f32x4* ezb = (f32x4*)enc + (size_t)bid * 4096;
        const f32x4 zf4 = {0.f, 0.f, 0.f, 0.f};
        #pragma unroll
        for (int j = 0; j < 16; ++j)
            __builtin_nontemporal_store(zf4, ezb + t + j * 256);
    }

    // ---- cross-wave merge + pair write ----
    if (t < 64) {
        float a1 = M1[0][t], a2 = M2[0][t];
        #pragma unroll
        for (int w2 = 1; w2 < 4; ++w2) {
            float b1 = M1[w2][t], b2 = M2[w2][t];
            float big = fmaxf(a1, b1);
            a2 = fmaxf(fminf(a1, b1), (a1 >= b1) ? a2 : b2);
            a1 = big;
        }
        f32x2 pr; pr[0] = a1; pr[1] = a2;
        pairs[(size_t)(tok0 + t) * 16 + ntile] = pr;
    }
}

// ---- k_refine: per-token global threshold + np-fp32-exact refine + epilogue ----
__global__ __launch_bounds__(256) void k_refine(
        const float* __restrict__ x, const float* __restrict__ w,
        const float* __restrict__ e2_np, const float* __restrict__ x2_np,
        const f32x2* __restrict__ pairs,
        float* __restrict__ out_idx, unsigned int* __restrict__ counts,
        float* enc, float* __restrict__ outq, float* __restrict__ loss_acc) {
    __shared__ float sred[4];
    const int t = threadIdx.x;
    const int wave = t >> 6, lane = t & 63;
    const int token = t >> 2, slot = t & 3;
    const int tok = blockIdx.x * 64 + token;

    // each of 4 slot-lanes loads 4 pairs (32B contiguous)
    f32x2 e[4];
    const f32x2* pr = pairs + (size_t)tok * 16 + slot * 4;
    #pragma unroll
    for (int k = 0; k < 4; ++k) e[k] = pr[k];
    float mx = e[0][0];
    #pragma unroll
    for (int k = 0; k < 4; ++k) mx = fmaxf(mx, fmaxf(e[k][0], e[k][1]));
    mx = fmaxf(mx, __shfl_xor(mx, 1));
    mx = fmaxf(mx, __shfl_xor(mx, 2));
    float thr = mx - MARGIN;

    float bd = 3.4e38f;
    int bi = 0x7fffffff;
    float x2 = x2_np[tok];
    const float4* xr = (const float4*)(x + (size_t)tok * DIM);
    #pragma unroll
    for (int k = 0; k < 4; ++k)
        #pragma unroll
        for (int h = 0; h < 2; ++h) {
            float v = e[k][h];
            if (v >= thr) {
                int code = (int)(__float_as_uint(v) & 4095u);
                const float4* wr = (const float4*)(w + (size_t)code * DIM);
                double dot = 0.0;
                for (int g = 0; g < 64; ++g) {
                    float4 xv = xr[g];
                    float4 wv = wr[g];
                    dot += (double)xv.x * (double)wv.x;
                    dot += (double)xv.y * (double)wv.y;
                    dot += (double)xv.z * (double)wv.z;
                    dot += (double)xv.w * (double)wv.w;
                }
                {
#pragma clang fp contract(off)
                    float M  = (float)dot;          // BLAS sgemm entry (~2e-9)
                    float S  = x2 + e2_np[code];    // np broadcast add (fp32)
                    float dd = S - 2.0f * M;        // fp32 sub -> ulp bucket
                    if (dd < bd || (dd == bd && code < bi)) { bd = dd; bi = code; }
                }
            }
        }
    // butterfly merge over the 4 slot-lanes (all converge)
    #pragma unroll
    for (int off = 1; off < 4; off <<= 1) {
        float ov = __shfl_xor(bd, off);
        int   oi = __shfl_xor(bi, off);
        if (ov < bd || (ov == bd && oi < bi)) { bd = ov; bi = oi; }
    }
    int fi = bi;
    if (slot == 0) {
        out_idx[tok] = (float)fi;
        atomicAdd(&counts[fi], 1u);
        if (enc)
            __builtin_nontemporal_store(1.0f, enc + (size_t)tok * N_EMB + fi);
    }

    // ---- epilogue: quantized gather + commitment loss ----
    {
        const f32x4* wr = (const f32x4*)(w + (size_t)fi * DIM);
        const f32x4* xr4 = (const f32x4*)(x + (size_t)tok * DIM);
        f32x4* oq = (f32x4*)(outq + (size_t)tok * DIM);
        float sse = 0.f;
        #pragma unroll
        for (int g0 = 0; g0 < 16; ++g0) {
            int g = slot * 16 + g0;
            f32x4 qv = wr[g];
            f32x4 xv = xr4[g];
            __builtin_nontemporal_store(qv, oq + g);
            float dx = qv.x - xv.x, dy = qv.y - xv.y;
            float dz = qv.z - xv.z, dw = qv.w - xv.w;
            sse += dx * dx + dy * dy + dz * dz + dw * dw;
        }
        #pragma unroll
        for (int off = 32; off > 0; off >>= 1) sse += __shfl_down(sse, off, 64);
        if (lane == 0) sred[wave] = sse;
    }
    __syncthreads();
    if (t == 0)
        atomicAdd(loss_acc, sred[0] + sred[1] + sred[2] + sred[3]);
}

// ---------------- one-hot encodings (fallback path only) ----------------
__global__ __launch_bounds__(256) void k_onehot(const float* __restrict__ out_idx,
                                                float* __restrict__ enc) {
    int token = blockIdx.x;
    int idx = (int)out_idx[token];
    float4* row = (float4*)(enc + (size_t)token * N_EMB);
    #pragma unroll
    for (int p = 0; p < 4; ++p) {
        int g = threadIdx.x + 256 * p;
        float4 v = make_float4(0.f, 0.f, 0.f, 0.f);
        int d0 = g * 4;
        if (idx >= d0 && idx < d0 + 4) ((float*)&v)[idx - d0] = 1.0f;
        row[g] = v;
    }
}

// ---------------- perplexity + loss finalize ----------------
__global__ __launch_bounds__(256) void k_final(const unsigned int* __restrict__ counts,
                                               const float* __restrict__ loss_acc,
                                               float* __restrict__ out_perp,
                                               float* __restrict__ out_loss) {
    __shared__ float sred[4];
    int t = threadIdx.x;
    float h = 0.f;
    for (int k = t; k < N_EMB; k += 256) {
        float p = (float)counts[k] * (1.0f / N_TOK);
        h += p * logf(p + 1e-10f);
    }
    #pragma unroll
    for (int off = 32; off > 0; off >>= 1) h += __shfl_down(h, off, 64);
    if ((t & 63) == 0) sred[t >> 6] = h;
    __syncthreads();
    if (t == 0) {
        float s = sred[0] + sred[1] + sred[2] + sred[3];
        *out_perp = expf(-s);
        *out_loss = loss_acc[0] * 1.25f / 8388608.0f;
    }
}

extern "C" void kernel_launch(void* const* d_in, const int* in_sizes, int n_in,
                              void* d_out, int out_size, void* d_ws, size_t ws_size,
                              hipStream_t stream) {
    const float* x = (const float*)d_in[0];
    const float* w = (const float*)d_in[1];
    float* out  = (float*)d_out;
    float* out0 = out;                       // quantized_st [32768*256]
    float* out1 = out0 + 8388608;            // perplexity   [1]
    float* out2 = out1 + 1;                  // encodings    [32768*4096]
    float* out3 = out2 + 134217728;          // indices      [32768] (as float)
    float* out4 = out3 + 32768;              // loss         [1]

    unsigned int* counts = (unsigned int*)d_ws;
    float* loss_acc = (float*)((char*)d_ws + 16384);
    float* e2_np    = (float*)((char*)d_ws + 16896);
    float* x2_np    = (float*)((char*)d_ws + 33280);

    // Primary: scratch in d_ws, enc zeroed by k_top2's fused NT drip + 1.0f
    // scatter in k_refine. Fallback (small ws): scratch aliases out2 -> no
    // fused enc, full-row k_onehot after refine.
    bool big_ws = ws_size >= (size_t)(24u * 1024u * 1024u);
    unsigned short *Xh, *Wh;
    f32x2* pairs;
    float* enc_arg;
    if (big_ws) {
        Xh = (unsigned short*)((char*)d_ws + (1u << 20));    // 16 MB
        Wh = Xh + 8388608;                                    // 2 MB
        pairs = (f32x2*)((char*)d_ws + 19u * 1024u * 1024u);  // 4 MB
        enc_arg = out2;
    } else {
        uintptr_t sb = ((uintptr_t)out2 + 255) & ~(uintptr_t)255;
        Xh = (unsigned short*)sb;
        Wh = Xh + 8388608;
        pairs = (f32x2*)(Wh + 1048576);
        enc_arg = nullptr;
    }

    hipMemsetAsync(d_ws, 0, 16640, stream);
    k_norm_np<<<N_EMB / 256, 256, 0, stream>>>(w, e2_np, N_EMB);
    k_norm_np<<<N_TOK / 256, 256, 0, stream>>>(x, x2_np, N_TOK);
    k_shuf1<<<N_TOK * DIM / 8 / 256, 256, 0, stream>>>(x, Xh);
    k_shuf1<<<N_EMB * DIM / 8 / 256, 256, 0, stream>>>(w, Wh);
    k_top2<<<(N_TOK / 64) * 16, 256, 0, stream>>>(Xh, Wh, pairs, enc_arg);
    k_refine<<<N_TOK / 64, 256, 0, stream>>>(x, w, e2_np, x2_np, pairs,
                                             out3, counts, enc_arg,
                                             out0, loss_acc);
    if (!big_ws)
        k_onehot<<<N_TOK, 256, 0, stream>>>(out3, out2);
    k_final<<<1, 256, 0, stream>>>(counts, loss_acc, out1, out4);
}

// Round 5
// 806.190 us; speedup vs baseline: 1.1844x; 1.0089x over previous
//
#include <hip/hip_runtime.h>

#define N_TOK 32768
#define N_EMB 4096
#define DIM 256

typedef short bf16x8 __attribute__((ext_vector_type(8)));
typedef float f32x4 __attribute__((ext_vector_type(4)));
typedef unsigned short us8 __attribute__((ext_vector_type(8)));

// ---------------- ws layout (primary, ws_size >= 20 MB) ----------------
// [0, 16384)        counts    uint[4096]
// [16384, 16388)    loss_acc  float
// [16896, 33280)    e2_np     float[4096]
// [33280, 164352)   x2_np     float[32768]
// [1 MB, 17 MB)     Xh        bf16[32768*256] MFMA-shuffled
// [17 MB, 19 MB)    Wh        bf16[4096*256]  MFMA-shuffled
// Fallback (small ws): Xh/Wh in encodings region + separate k_onehot.

static __device__ __forceinline__ unsigned short f2bf(float f) {
    unsigned int u = __float_as_uint(f);
    u = (u + 0x7fffu + ((u >> 16) & 1u)) >> 16;   // RTN-even
    return (unsigned short)u;
}

// pack 6-bit id into low mantissa bits (<=64 ulp perturbation << 1.5e-4 margin)
static __device__ __forceinline__ float pkid(float x, unsigned int id) {
    return __uint_as_float((__float_as_uint(x) & ~63u) | id);
}

// ---------------- numpy-pairwise fp32 row norms (r3-proven bit-exact) ------
__device__ __forceinline__ float pw128_sq(const float4* a4) {
#pragma clang fp contract(off)
    float4 v0 = a4[0], v1 = a4[1];
    float r0 = v0.x * v0.x, r1 = v0.y * v0.y, r2 = v0.z * v0.z, r3 = v0.w * v0.w;
    float r4 = v1.x * v1.x, r5 = v1.y * v1.y, r6 = v1.z * v1.z, r7 = v1.w * v1.w;
    #pragma unroll
    for (int i = 1; i < 16; ++i) {
        v0 = a4[2 * i]; v1 = a4[2 * i + 1];
        float s;
        s = v0.x * v0.x; r0 += s;
        s = v0.y * v0.y; r1 += s;
        s = v0.z * v0.z; r2 += s;
        s = v0.w * v0.w; r3 += s;
        s = v1.x * v1.x; r4 += s;
        s = v1.y * v1.y; r5 += s;
        s = v1.z * v1.z; r6 += s;
        s = v1.w * v1.w; r7 += s;
    }
    return ((r0 + r1) + (r2 + r3)) + ((r4 + r5) + (r6 + r7));
}

// ---- fused prep: bf16 MFMA-shuffle + bit-exact row norms, x and w in one ----
// grid = N_TOK/16 + N_EMB/16 = 2304 blocks. Block <-> one 16-row tile:
// 256 threads shuffle (each 2x us8), threads 0..15 re-read their (L1-hot)
// row with the r3-proven pw128_sq order. Replaces 4 dispatches with 1.
__global__ __launch_bounds__(256) void k_prep(const float* __restrict__ x,
                                              const float* __restrict__ w,
                                              unsigned short* __restrict__ Xh,
                                              unsigned short* __restrict__ Wh,
                                              float* __restrict__ x2_np,
                                              float* __restrict__ e2_np) {
    int bid = blockIdx.x;
    const float* src;
    unsigned short* dst;
    float* ndst;
    int T;
    if (bid < N_TOK / 16) { src = x; dst = Xh; ndst = x2_np; T = bid; }
    else                  { src = w; dst = Wh; ndst = e2_np; T = bid - N_TOK / 16; }
    const int t = threadIdx.x, lane = t & 63, g = t >> 6;
    #pragma unroll
    for (int cc = 0; cc < 2; ++cc) {
        int C = g * 2 + cc;
        int row = T * 16 + (lane & 15);
        int col = C * 32 + (lane >> 4) * 8;
        const float* s = src + (size_t)row * DIM + col;
        us8 h;
        #pragma unroll
        for (int j = 0; j < 8; ++j) h[j] = f2bf(s[j]);
        *(us8*)(dst + ((size_t)(T * 8 + C) * 64 + lane) * 8) = h;
    }
    if (t < 16) {
        int row = T * 16 + t;
        const float4* a = (const float4*)(src + (size_t)row * DIM);
        float lo = pw128_sq(a);
        float hi = pw128_sq(a + 32);
        ndst[row] = lo + hi;
    }
}

// ---- fused MFMA scoring: r1-proven structure (32 tok/block, 1024 blocks) ----
// vs r1: (1) enc zero-drip REMOVED from the jt loop (r3 A/B: -28us; it shared
// the vmcnt FIFO with bh loads) -> post-threshold NT burst overlapped with the
// refine phase's gather latency; barriers order it before the 1.0f scatter.
// (2) top-2 update uses the exact max3/med3 tournament (r2-proven merge).
__global__ __launch_bounds__(256, 4) void k_score_mfma(
        const float* __restrict__ x, const float* __restrict__ w,
        const float* __restrict__ e2_np, const float* __restrict__ x2_np,
        const unsigned short* __restrict__ Xh,
        const unsigned short* __restrict__ Wh,
        float* __restrict__ out_idx, unsigned int* __restrict__ counts,
        float* enc,                       // nullable: fused one-hot
        float* __restrict__ outq, float* __restrict__ loss_acc) {
    __shared__ __align__(16) short Abuf[8192];   // [tile(2)][C(8)][lane][8] = 16 KB
    __shared__ float Tmax[4][32];
    __shared__ unsigned int ccnt[32];
    __shared__ int clist[32][16];
    __shared__ float Red_d[32 * 8];
    __shared__ int   Red_i[32 * 8];
    __shared__ float sred[4];

    const int t = threadIdx.x;
    const int wave = t >> 6, lane = t & 63;
    const int tok0 = blockIdx.x * 32;
    const int q = lane >> 4, c = lane & 15;

    // ---- stage A (2 tiles x 8 chunks x 1KB), r7-proven ----
    #pragma unroll
    for (int i = 0; i < 4; ++i) {
        int idx = wave * 4 + i;             // 0..15
        int tile = idx >> 3, C = idx & 7;
        int Tg = blockIdx.x * 2 + tile;
        const unsigned short* src = Xh + ((size_t)(Tg * 8 + C) * 64 + lane) * 8;
        __builtin_amdgcn_global_load_lds(
            (const __attribute__((address_space(1))) unsigned int*)src,
            (__attribute__((address_space(3))) unsigned int*)(Abuf + idx * 512),
            16, 0, 0);
    }
    if (t < 32) ccnt[t] = 0;
    __syncthreads();

    // ---- single pass: per-token packed top-2 (pure MFMA + loads) ----
    float vmax[8], v2[8];
    #pragma unroll
    for (int s = 0; s < 8; ++s) { vmax[s] = -3.4e38f; v2[s] = -3.4e38f; }
    for (int jt = 0; jt < N_EMB; jt += 256) {
        const int U0 = (jt >> 4) + wave * 4;
        f32x4 acc[2][4] = {};
        #pragma unroll
        for (int C = 0; C < 8; ++C) {
            bf16x8 ah[2], bh[4];
            #pragma unroll
            for (int m = 0; m < 2; ++m)
                ah[m] = *(const bf16x8*)(Abuf + (size_t)(m * 8 + C) * 512 + lane * 8);
            #pragma unroll
            for (int n = 0; n < 4; ++n)
                bh[n] = *(const bf16x8*)(Wh + (((size_t)(U0 + n) * 8 + C) * 64 + lane) * 8);
            #pragma unroll
            for (int m = 0; m < 2; ++m)
                #pragma unroll
                for (int n = 0; n < 4; ++n)
                    acc[m][n] = __builtin_amdgcn_mfma_f32_16x16x32_bf16(ah[m], bh[n], acc[m][n], 0, 0, 0);
        }
        // packed top-2 update via exact max3/med3 tournament (r2-proven)
        {
            unsigned int idb = ((unsigned int)jt >> 8) << 2;
            #pragma unroll
            for (int m = 0; m < 2; ++m)
                #pragma unroll
                for (int r = 0; r < 4; ++r) {
                    int s = m * 4 + r;
                    float p0 = pkid(acc[m][0][r], idb + 0);
                    float p1 = pkid(acc[m][1][r], idb + 1);
                    float p2 = pkid(acc[m][2][r], idb + 2);
                    float p3 = pkid(acc[m][3][r], idb + 3);
                    float t1a = fmaxf(fmaxf(vmax[s], p0), p1);
                    float t2a = __builtin_amdgcn_fmed3f(vmax[s], p0, p1);
                    float t1b = fmaxf(fmaxf(v2[s], p2), p3);
                    float t2b = __builtin_amdgcn_fmed3f(v2[s], p2, p3);
                    vmax[s] = fmaxf(t1a, t1b);
                    v2[s]   = fmaxf(fmaxf(fminf(t1a, t1b), t2a), t2b);
                }
        }
    }
    // reduce over the 16 c-lanes of each q-group (keep per-thread vmax/v2!)
    float rmax[8];
    #pragma unroll
    for (int s = 0; s < 8; ++s) rmax[s] = vmax[s];
    #pragma unroll
    for (int off = 1; off < 16; off <<= 1)
        #pragma unroll
        for (int s = 0; s < 8; ++s)
            rmax[s] = fmaxf(rmax[s], __shfl_xor(rmax[s], off));
    if (c == 0) {
        #pragma unroll
        for (int m = 0; m < 2; ++m)
            #pragma unroll
            for (int r = 0; r < 4; ++r)
                Tmax[wave][m * 16 + q * 4 + r] = rmax[m * 4 + r];
    }
    __syncthreads();
    if (t < 32) {
        float mx = fmaxf(fmaxf(Tmax[0][t], Tmax[1][t]),
                         fmaxf(Tmax[2][t], Tmax[3][t]));
        Tmax[0][t] = mx - 1.5e-4f;     // threshold (r6/r7-proven margin)
    }
    __syncthreads();
    float thr[8];
    #pragma unroll
    for (int m = 0; m < 2; ++m)
        #pragma unroll
        for (int r = 0; r < 4; ++r)
            thr[m * 4 + r] = Tmax[0][m * 16 + q * 4 + r];

    // ---- candidate push from registers (no recompute pass) ----
    #pragma unroll
    for (int s = 0; s < 8; ++s) {
        int m = s >> 2, r = s & 3;
        int tokl = m * 16 + q * 4 + r;
        #pragma unroll
        for (int h = 0; h < 2; ++h) {
            float pv = h ? v2[s] : vmax[s];
            if (pv >= thr[s]) {
                unsigned int id = __float_as_uint(pv) & 63u;
                int code = ((int)(id >> 2) * 16 + wave * 4 + (int)(id & 3u)) * 16 + c;
                unsigned int p = atomicAdd(&ccnt[tokl], 1u);
                if (p < 16) clist[tokl][p] = code;
            }
        }
    }
    __syncthreads();

    // ---- fused enc zero-fill (512 KB/block), overlapped with refine ----
    // NT stores issue here; the refine phase's f64 gathers hide the drain.
    // The barrier after Red_* (vmcnt(0) drain) orders them before the 1.0f
    // scatter in the epilogue (r0/r1-proven same-kernel pattern).
    if (enc) {
        f32x4* ezb = (f32x4*)(enc + (size_t)tok0 * N_EMB);   // 32 rows
        const f32x4 zf4 = {0.f, 0.f, 0.f, 0.f};
        #pragma unroll
        for (int j = 0; j < 128; ++j)
            __builtin_nontemporal_store(zf4, ezb + t + j * 256);
    }

    // ---- np-fp32-exact refinement: 8 threads/token over the list ----
    {
        int token = t >> 3, slot = t & 7;
        int cnt = (int)ccnt[token]; if (cnt > 16) cnt = 16;
        float bd = 3.4e38f;
        int bi = 0x7fffffff;
        float x2 = x2_np[tok0 + token];
        const float4* xr = (const float4*)(x + (size_t)(tok0 + token) * DIM);
        for (int k = slot; k < cnt; k += 8) {
            int code = clist[token][k];
            const float4* wr = (const float4*)(w + (size_t)code * DIM);
            double dot = 0.0;
            for (int g = 0; g < 64; ++g) {
                float4 xv = xr[g];
                float4 wv = wr[g];
                dot += (double)xv.x * (double)wv.x;
                dot += (double)xv.y * (double)wv.y;
                dot += (double)xv.z * (double)wv.z;
                dot += (double)xv.w * (double)wv.w;
            }
            {
#pragma clang fp contract(off)
                float M  = (float)dot;          // BLAS sgemm entry (~2e-9)
                float S  = x2 + e2_np[code];    // np broadcast add (fp32)
                float dd = S - 2.0f * M;        // fp32 sub -> ulp bucket
                if (dd < bd || (dd == bd && code < bi)) { bd = dd; bi = code; }
            }
        }
        Red_d[token * 8 + slot] = bd;
        Red_i[token * 8 + slot] = bi;
    }
    __syncthreads();
    if (t < 32) {
        float fv = Red_d[t * 8];
        int   fi = Red_i[t * 8];
        #pragma unroll
        for (int k = 1; k < 8; ++k) {
            float v = Red_d[t * 8 + k];
            int  ii = Red_i[t * 8 + k];
            if (v < fv || (v == fv && ii < fi)) { fv = v; fi = ii; }
        }
        out_idx[tok0 + t] = (float)fi;
        atomicAdd(&counts[fi], 1u);
        ccnt[t] = (unsigned int)fi;   // publish for epilogue
    }
    __syncthreads();

    // ---- epilogue: 1.0f scatter + quantized gather + commitment loss ----
    {
        int token = t >> 3, slot = t & 7;
        int fi = (int)ccnt[token];
        // zero stores drained at the preceding barriers' vmcnt(0);
        // same-XCD L2 ordering makes this 1.0f land after them.
        if (enc && slot == 0)
            __builtin_nontemporal_store(1.0f, enc + (size_t)(tok0 + token) * N_EMB + fi);
        const f32x4* wr = (const f32x4*)(w + (size_t)fi * DIM);
        const f32x4* xr = (const f32x4*)(x + (size_t)(tok0 + token) * DIM);
        f32x4* oq = (f32x4*)(outq + (size_t)(tok0 + token) * DIM);
        float sse = 0.f;
        #pragma unroll
        for (int g0 = 0; g0 < 8; ++g0) {
            int g = slot * 8 + g0;
            f32x4 qv = wr[g];
            f32x4 xv = xr[g];
            __builtin_nontemporal_store(qv, oq + g);
            float dx = qv.x - xv.x, dy = qv.y - xv.y;
            float dz = qv.z - xv.z, dw = qv.w - xv.w;
            sse += dx * dx + dy * dy + dz * dz + dw * dw;
        }
        #pragma unroll
        for (int off = 32; off > 0; off >>= 1) sse += __shfl_down(sse, off, 64);
        if (lane == 0) sred[wave] = sse;
    }
    __syncthreads();
    if (t == 0)
        atomicAdd(loss_acc, sred[0] + sred[1] + sred[2] + sred[3]);
}

// ---------------- one-hot encodings (fallback path only) ----------------
__global__ __launch_bounds__(256) void k_onehot(const float* __restrict__ out_idx,
                                                float* __restrict__ enc) {
    int token = blockIdx.x;
    int idx = (int)out_idx[token];
    float4* row = (float4*)(enc + (size_t)token * N_EMB);
    #pragma unroll
    for (int p = 0; p < 4; ++p) {
        int g = threadIdx.x + 256 * p;
        float4 v = make_float4(0.f, 0.f, 0.f, 0.f);
        int d0 = g * 4;
        if (idx >= d0 && idx < d0 + 4) ((float*)&v)[idx - d0] = 1.0f;
        row[g] = v;
    }
}

// ---------------- perplexity + loss finalize ----------------
__global__ __launch_bounds__(256) void k_final(const unsigned int* __restrict__ counts,
                                               const float* __restrict__ loss_acc,
                                               float* __restrict__ out_perp,
                                               float* __restrict__ out_loss) {
    __shared__ float sred[4];
    int t = threadIdx.x;
    float h = 0.f;
    for (int k = t; k < N_EMB; k += 256) {
        float p = (float)counts[k] * (1.0f / N_TOK);
        h += p * logf(p + 1e-10f);
    }
    #pragma unroll
    for (int off = 32; off > 0; off >>= 1) h += __shfl_down(h, off, 64);
    if ((t & 63) == 0) sred[t >> 6] = h;
    __syncthreads();
    if (t == 0) {
        float s = sred[0] + sred[1] + sred[2] + sred[3];
        *out_perp = expf(-s);
        *out_loss = loss_acc[0] * 1.25f / 8388608.0f;
    }
}

extern "C" void kernel_launch(void* const* d_in, const int* in_sizes, int n_in,
                              void* d_out, int out_size, void* d_ws, size_t ws_size,
                              hipStream_t stream) {
    const float* x = (const float*)d_in[0];
    const float* w = (const float*)d_in[1];
    float* out  = (float*)d_out;
    float* out0 = out;                       // quantized_st [32768*256]
    float* out1 = out0 + 8388608;            // perplexity   [1]
    float* out2 = out1 + 1;                  // encodings    [32768*4096]
    float* out3 = out2 + 134217728;          // indices      [32768] (as float)
    float* out4 = out3 + 32768;              // loss         [1]

    unsigned int* counts = (unsigned int*)d_ws;
    float* loss_acc = (float*)((char*)d_ws + 16384);
    float* e2_np    = (float*)((char*)d_ws + 16896);
    float* x2_np    = (float*)((char*)d_ws + 33280);

    // Primary: scratch in d_ws, enc zeroed by k_score's fused post-threshold
    // NT burst + 1.0f scatter. Fallback (small ws): scratch aliases out2 ->
    // no fused enc, full-row k_onehot after score.
    bool big_ws = ws_size >= (size_t)(20u * 1024u * 1024u);
    unsigned short *Xh, *Wh;
    float* enc_arg;
    if (big_ws) {
        Xh = (unsigned short*)((char*)d_ws + (1u << 20));   // 16 MB
        Wh = Xh + 8388608;                                   // 2 MB
        enc_arg = out2;
    } else {
        uintptr_t sb = ((uintptr_t)out2 + 255) & ~(uintptr_t)255;
        Xh = (unsigned short*)sb;
        Wh = Xh + 8388608;
        enc_arg = nullptr;
    }

    hipMemsetAsync(d_ws, 0, 16640, stream);
    k_prep<<<N_TOK / 16 + N_EMB / 16, 256, 0, stream>>>(x, w, Xh, Wh, x2_np, e2_np);
    k_score_mfma<<<N_TOK / 32, 256, 0, stream>>>(x, w, e2_np, x2_np, Xh, Wh,
                                                 out3, counts, enc_arg,
                                                 out0, loss_acc);
    if (!big_ws)
        k_onehot<<<N_TOK, 256, 0, stream>>>(out3, out2);
    k_final<<<1, 256, 0, stream>>>(counts, loss_acc, out1, out4);
}

// Round 6
// 783.625 us; speedup vs baseline: 1.2185x; 1.0288x over previous
//
#include <hip/hip_runtime.h>

#define N_TOK 32768
#define N_EMB 4096
#define DIM 256

typedef short bf16x8 __attribute__((ext_vector_type(8)));
typedef float f32x4 __attribute__((ext_vector_type(4)));
typedef unsigned short us8 __attribute__((ext_vector_type(8)));

// ---------------- ws layout (primary, ws_size >= 20 MB) ----------------
// [0, 16384)        counts    uint[4096]
// [16384, 16388)    loss_acc  float
// [16896, 33280)    e2_np     float[4096]
// [33280, 164352)   x2_np     float[32768]
// [1 MB, 17 MB)     Xh        bf16[32768*256] MFMA-shuffled
// [17 MB, 19 MB)    Wh        bf16[4096*256]  MFMA-shuffled
// Fallback (small ws): Xh/Wh in encodings region + separate k_onehot.

static __device__ __forceinline__ unsigned short f2bf(float f) {
    unsigned int u = __float_as_uint(f);
    u = (u + 0x7fffu + ((u >> 16) & 1u)) >> 16;   // RTN-even
    return (unsigned short)u;
}

// ---------------- numpy-pairwise fp32 row norms (r3-proven bit-exact) ------
__device__ __forceinline__ float pw128_sq(const float4* a4) {
#pragma clang fp contract(off)
    float4 v0 = a4[0], v1 = a4[1];
    float r0 = v0.x * v0.x, r1 = v0.y * v0.y, r2 = v0.z * v0.z, r3 = v0.w * v0.w;
    float r4 = v1.x * v1.x, r5 = v1.y * v1.y, r6 = v1.z * v1.z, r7 = v1.w * v1.w;
    #pragma unroll
    for (int i = 1; i < 16; ++i) {
        v0 = a4[2 * i]; v1 = a4[2 * i + 1];
        float s;
        s = v0.x * v0.x; r0 += s;
        s = v0.y * v0.y; r1 += s;
        s = v0.z * v0.z; r2 += s;
        s = v0.w * v0.w; r3 += s;
        s = v1.x * v1.x; r4 += s;
        s = v1.y * v1.y; r5 += s;
        s = v1.z * v1.z; r6 += s;
        s = v1.w * v1.w; r7 += s;
    }
    return ((r0 + r1) + (r2 + r3)) + ((r4 + r5) + (r6 + r7));
}

// ---- fused prep: bf16 MFMA-shuffle + bit-exact row norms (r5-verified) ----
// grid = N_TOK/16 + N_EMB/16 = 2304 blocks. Block <-> one 16-row tile:
// 256 threads shuffle (each 2x us8), threads 0..15 compute the r3-proven
// pw128_sq row norms on L1-hot rows. Replaces 4 dispatches with 1.
__global__ __launch_bounds__(256) void k_prep(const float* __restrict__ x,
                                              const float* __restrict__ w,
                                              unsigned short* __restrict__ Xh,
                                              unsigned short* __restrict__ Wh,
                                              float* __restrict__ x2_np,
                                              float* __restrict__ e2_np) {
    int bid = blockIdx.x;
    const float* src;
    unsigned short* dst;
    float* ndst;
    int T;
    if (bid < N_TOK / 16) { src = x; dst = Xh; ndst = x2_np; T = bid; }
    else                  { src = w; dst = Wh; ndst = e2_np; T = bid - N_TOK / 16; }
    const int t = threadIdx.x, lane = t & 63, g = t >> 6;
    #pragma unroll
    for (int cc = 0; cc < 2; ++cc) {
        int C = g * 2 + cc;
        int row = T * 16 + (lane & 15);
        int col = C * 32 + (lane >> 4) * 8;
        const float* s = src + (size_t)row * DIM + col;
        us8 h;
        #pragma unroll
        for (int j = 0; j < 8; ++j) h[j] = f2bf(s[j]);
        *(us8*)(dst + ((size_t)(T * 8 + C) * 64 + lane) * 8) = h;
    }
    if (t < 16) {
        int row = T * 16 + t;
        const float4* a = (const float4*)(src + (size_t)row * DIM);
        float lo = pw128_sq(a);
        float hi = pw128_sq(a + 32);
        ndst[row] = lo + hi;
    }
}

// ---- fused MFMA scoring: r1-proven structure VERBATIM (32 tok/block,
// drip-in-loop one-hot zero-fill, branchy top-2), with one change:
// __launch_bounds__(256,5) -> 5 blocks/CU (r3 counters proved the jt loop is
// load-latency-bound with all pipes <8%; 25% more waves to hide bh latency).
// r5 lesson: the post-threshold NT burst fills the store queue and serializes
// ~85us of HBM writes; the r1 drip (8 stores/jt, covered by 32 MFMAs) wins.
__global__ __launch_bounds__(256, 5) void k_score_mfma(
        const float* __restrict__ x, const float* __restrict__ w,
        const float* __restrict__ e2_np, const float* __restrict__ x2_np,
        const unsigned short* __restrict__ Xh,
        const unsigned short* __restrict__ Wh,
        float* __restrict__ out_idx, unsigned int* __restrict__ counts,
        float* enc,                       // nullable: fused one-hot
        float* __restrict__ outq, float* __restrict__ loss_acc) {
    __shared__ __align__(16) short Abuf[8192];   // [tile(2)][C(8)][lane][8] = 16 KB
    __shared__ float Tmax[4][32];
    __shared__ unsigned int ccnt[32];
    __shared__ int clist[32][16];
    __shared__ float Red_d[32 * 8];
    __shared__ int   Red_i[32 * 8];
    __shared__ float sred[4];

    const int t = threadIdx.x;
    const int wave = t >> 6, lane = t & 63;
    const int tok0 = blockIdx.x * 32;
    const int q = lane >> 4, c = lane & 15;

    // ---- stage A (2 tiles x 8 chunks x 1KB), r7-proven ----
    #pragma unroll
    for (int i = 0; i < 4; ++i) {
        int idx = wave * 4 + i;             // 0..15
        int tile = idx >> 3, C = idx & 7;
        int Tg = blockIdx.x * 2 + tile;
        const unsigned short* src = Xh + ((size_t)(Tg * 8 + C) * 64 + lane) * 8;
        __builtin_amdgcn_global_load_lds(
            (const __attribute__((address_space(1))) unsigned int*)src,
            (__attribute__((address_space(3))) unsigned int*)(Abuf + idx * 512),
            16, 0, 0);
    }
    if (t < 32) ccnt[t] = 0;
    __syncthreads();

    f32x4* ez = enc ? (f32x4*)(enc + (size_t)tok0 * N_EMB) : (f32x4*)0;
    const f32x4 zf4 = {0.f, 0.f, 0.f, 0.f};

    // ---- single pass: per-token packed top-2; one-hot zero-fill drip-fed ----
    float vmax[8], v2[8];
    #pragma unroll
    for (int s = 0; s < 8; ++s) { vmax[s] = -3.4e38f; v2[s] = -3.4e38f; }
    for (int jt = 0; jt < N_EMB; jt += 256) {
        const int U0 = (jt >> 4) + wave * 4;
        f32x4 acc[2][4] = {};
        #pragma unroll
        for (int C = 0; C < 8; ++C) {
            bf16x8 ah[2], bh[4];
            #pragma unroll
            for (int m = 0; m < 2; ++m)
                ah[m] = *(const bf16x8*)(Abuf + (size_t)(m * 8 + C) * 512 + lane * 8);
            #pragma unroll
            for (int n = 0; n < 4; ++n)
                bh[n] = *(const bf16x8*)(Wh + (((size_t)(U0 + n) * 8 + C) * 64 + lane) * 8);
            #pragma unroll
            for (int m = 0; m < 2; ++m)
                #pragma unroll
                for (int n = 0; n < 4; ++n)
                    acc[m][n] = __builtin_amdgcn_mfma_f32_16x16x32_bf16(ah[m], bh[n], acc[m][n], 0, 0, 0);
        }
        // packed top-2 update: low 6 mantissa bits carry (jtTile, n)
        {
            unsigned int idb = ((unsigned int)jt >> 8) << 2;
            #pragma unroll
            for (int m = 0; m < 2; ++m)
                #pragma unroll
                for (int n = 0; n < 4; ++n)
                    #pragma unroll
                    for (int r = 0; r < 4; ++r) {
                        float p = __uint_as_float(
                            (__float_as_uint(acc[m][n][r]) & ~63u) | (idb + (unsigned)n));
                        int s = m * 4 + r;
                        if (p > vmax[s]) { v2[s] = vmax[s]; vmax[s] = p; }
                        else if (p > v2[s]) v2[s] = p;
                    }
        }
        if (ez) {   // 8 x 16B nt zero-stores per thread per jt = 512 KB/block total
            int base = (jt >> 8) * 8 * 256 + t;
            #pragma unroll
            for (int j = 0; j < 8; ++j)
                __builtin_nontemporal_store(zf4, ez + base + j * 256);
        }
    }
    // reduce over the 16 c-lanes of each q-group (keep per-thread vmax/v2!)
    float rmax[8];
    #pragma unroll
    for (int s = 0; s < 8; ++s) rmax[s] = vmax[s];
    #pragma unroll
    for (int off = 1; off < 16; off <<= 1)
        #pragma unroll
        for (int s = 0; s < 8; ++s)
            rmax[s] = fmaxf(rmax[s], __shfl_xor(rmax[s], off));
    if (c == 0) {
        #pragma unroll
        for (int m = 0; m < 2; ++m)
            #pragma unroll
            for (int r = 0; r < 4; ++r)
                Tmax[wave][m * 16 + q * 4 + r] = rmax[m * 4 + r];
    }
    __syncthreads();
    if (t < 32) {
        float mx = fmaxf(fmaxf(Tmax[0][t], Tmax[1][t]),
                         fmaxf(Tmax[2][t], Tmax[3][t]));
        Tmax[0][t] = mx - 1.5e-4f;     // threshold (r6/r7-proven margin)
    }
    __syncthreads();
    float thr[8];
    #pragma unroll
    for (int m = 0; m < 2; ++m)
        #pragma unroll
        for (int r = 0; r < 4; ++r)
            thr[m * 4 + r] = Tmax[0][m * 16 + q * 4 + r];

    // ---- candidate push from registers (no recompute pass) ----
    #pragma unroll
    for (int s = 0; s < 8; ++s) {
        int m = s >> 2, r = s & 3;
        int tokl = m * 16 + q * 4 + r;
        #pragma unroll
        for (int h = 0; h < 2; ++h) {
            float pv = h ? v2[s] : vmax[s];
            if (pv >= thr[s]) {
                unsigned int id = __float_as_uint(pv) & 63u;
                int code = ((int)(id >> 2) * 16 + wave * 4 + (int)(id & 3u)) * 16 + c;
                unsigned int p = atomicAdd(&ccnt[tokl], 1u);
                if (p < 16) clist[tokl][p] = code;
            }
        }
    }
    __syncthreads();

    // ---- np-fp32-exact refinement: 8 threads/token over the list ----
    {
        int token = t >> 3, slot = t & 7;
        int cnt = (int)ccnt[token]; if (cnt > 16) cnt = 16;
        float bd = 3.4e38f;
        int bi = 0x7fffffff;
        float x2 = x2_np[tok0 + token];
        const float4* xr = (const float4*)(x + (size_t)(tok0 + token) * DIM);
        for (int k = slot; k < cnt; k += 8) {
            int code = clist[token][k];
            const float4* wr = (const float4*)(w + (size_t)code * DIM);
            double dot = 0.0;
            for (int g = 0; g < 64; ++g) {
                float4 xv = xr[g];
                float4 wv = wr[g];
                dot += (double)xv.x * (double)wv.x;
                dot += (double)xv.y * (double)wv.y;
                dot += (double)xv.z * (double)wv.z;
                dot += (double)xv.w * (double)wv.w;
            }
            {
#pragma clang fp contract(off)
                float M  = (float)dot;          // BLAS sgemm entry (~2e-9)
                float S  = x2 + e2_np[code];    // np broadcast add (fp32)
                float dd = S - 2.0f * M;        // fp32 sub -> ulp bucket
                if (dd < bd || (dd == bd && code < bi)) { bd = dd; bi = code; }
            }
        }
        Red_d[token * 8 + slot] = bd;
        Red_i[token * 8 + slot] = bi;
    }
    __syncthreads();
    if (t < 32) {
        float fv = Red_d[t * 8];
        int   fi = Red_i[t * 8];
        #pragma unroll
        for (int k = 1; k < 8; ++k) {
            float v = Red_d[t * 8 + k];
            int  ii = Red_i[t * 8 + k];
            if (v < fv || (v == fv && ii < fi)) { fv = v; fi = ii; }
        }
        out_idx[tok0 + t] = (float)fi;
        atomicAdd(&counts[fi], 1u);
        ccnt[t] = (unsigned int)fi;   // publish for epilogue
    }
    __syncthreads();

    // ---- epilogue: 1.0f scatter + quantized gather + commitment loss ----
    {
        int token = t >> 3, slot = t & 7;
        int fi = (int)ccnt[token];
        // zero-stores for this row drained at the Tmax __syncthreads (vmcnt(0));
        // same-XCD L2 ordering makes this 1.0f land after them.
        if (enc && slot == 0)
            __builtin_nontemporal_store(1.0f, enc + (size_t)(tok0 + token) * N_EMB + fi);
        const f32x4* wr = (const f32x4*)(w + (size_t)fi * DIM);
        const f32x4* xr = (const f32x4*)(x + (size_t)(tok0 + token) * DIM);
        f32x4* oq = (f32x4*)(outq + (size_t)(tok0 + token) * DIM);
        float sse = 0.f;
        #pragma unroll
        for (int g0 = 0; g0 < 8; ++g0) {
            int g = slot * 8 + g0;
            f32x4 qv = wr[g];
            f32x4 xv = xr[g];
            __builtin_nontemporal_store(qv, oq + g);
            float dx = qv.x - xv.x, dy = qv.y - xv.y;
            float dz = qv.z - xv.z, dw = qv.w - xv.w;
            sse += dx * dx + dy * dy + dz * dz + dw * dw;
        }
        #pragma unroll
        for (int off = 32; off > 0; off >>= 1) sse += __shfl_down(sse, off, 64);
        if (lane == 0) sred[wave] = sse;
    }
    __syncthreads();
    if (t == 0)
        atomicAdd(loss_acc, sred[0] + sred[1] + sred[2] + sred[3]);
}

// ---------------- one-hot encodings (fallback path only) ----------------
__global__ __launch_bounds__(256) void k_onehot(const float* __restrict__ out_idx,
                                                float* __restrict__ enc) {
    int token = blockIdx.x;
    int idx = (int)out_idx[token];
    float4* row = (float4*)(enc + (size_t)token * N_EMB);
    #pragma unroll
    for (int p = 0; p < 4; ++p) {
        int g = threadIdx.x + 256 * p;
        float4 v = make_float4(0.f, 0.f, 0.f, 0.f);
        int d0 = g * 4;
        if (idx >= d0 && idx < d0 + 4) ((float*)&v)[idx - d0] = 1.0f;
        row[g] = v;
    }
}

// ---------------- perplexity + loss finalize ----------------
__global__ __launch_bounds__(256) void k_final(const unsigned int* __restrict__ counts,
                                               const float* __restrict__ loss_acc,
                                               float* __restrict__ out_perp,
                                               float* __restrict__ out_loss) {
    __shared__ float sred[4];
    int t = threadIdx.x;
    float h = 0.f;
    for (int k = t; k < N_EMB; k += 256) {
        float p = (float)counts[k] * (1.0f / N_TOK);
        h += p * logf(p + 1e-10f);
    }
    #pragma unroll
    for (int off = 32; off > 0; off >>= 1) h += __shfl_down(h, off, 64);
    if ((t & 63) == 0) sred[t >> 6] = h;
    __syncthreads();
    if (t == 0) {
        float s = sred[0] + sred[1] + sred[2] + sred[3];
        *out_perp = expf(-s);
        *out_loss = loss_acc[0] * 1.25f / 8388608.0f;
    }
}

extern "C" void kernel_launch(void* const* d_in, const int* in_sizes, int n_in,
                              void* d_out, int out_size, void* d_ws, size_t ws_size,
                              hipStream_t stream) {
    const float* x = (const float*)d_in[0];
    const float* w = (const float*)d_in[1];
    float* out  = (float*)d_out;
    float* out0 = out;                       // quantized_st [32768*256]
    float* out1 = out0 + 8388608;            // perplexity   [1]
    float* out2 = out1 + 1;                  // encodings    [32768*4096]
    float* out3 = out2 + 134217728;          // indices      [32768] (as float)
    float* out4 = out3 + 32768;              // loss         [1]

    unsigned int* counts = (unsigned int*)d_ws;
    float* loss_acc = (float*)((char*)d_ws + 16384);
    float* e2_np    = (float*)((char*)d_ws + 16896);
    float* x2_np    = (float*)((char*)d_ws + 33280);

    // Primary: scratch in d_ws, enc zeroed by the r1-proven drip inside the
    // score jt-loop + 1.0f scatter. Fallback (small ws): scratch aliases
    // out2 -> no fused enc, full-row k_onehot after score.
    bool big_ws = ws_size >= (size_t)(20u * 1024u * 1024u);
    unsigned short *Xh, *Wh;
    float* enc_arg;
    if (big_ws) {
        Xh = (unsigned short*)((char*)d_ws + (1u << 20));   // 16 MB
        Wh = Xh + 8388608;                                   // 2 MB
        enc_arg = out2;
    } else {
        uintptr_t sb = ((uintptr_t)out2 + 255) & ~(uintptr_t)255;
        Xh = (unsigned short*)sb;
        Wh = Xh + 8388608;
        enc_arg = nullptr;
    }

    hipMemsetAsync(d_ws, 0, 16640, stream);
    k_prep<<<N_TOK / 16 + N_EMB / 16, 256, 0, stream>>>(x, w, Xh, Wh, x2_np, e2_np);
    k_score_mfma<<<N_TOK / 32, 256, 0, stream>>>(x, w, e2_np, x2_np, Xh, Wh,
                                                 out3, counts, enc_arg,
                                                 out0, loss_acc);
    if (!big_ws)
        k_onehot<<<N_TOK, 256, 0, stream>>>(out3, out2);
    k_final<<<1, 256, 0, stream>>>(counts, loss_acc, out1, out4);
}

// Round 8
// 734.745 us; speedup vs baseline: 1.2996x; 1.0665x over previous
//
#include <hip/hip_runtime.h>

#define N_TOK 32768
#define N_EMB 4096
#define DIM 256

typedef short bf16x8 __attribute__((ext_vector_type(8)));
typedef float f32x4 __attribute__((ext_vector_type(4)));
typedef unsigned short us8 __attribute__((ext_vector_type(8)));

// ---------------- ws layout (primary, ws_size >= 20 MB) ----------------
// [0, 16384)        counts    uint[4096]
// [16384, 16388)    loss_acc  float
// [16896, 33280)    e2_np     float[4096]
// [17 MB, 19 MB)    Wh        bf16[4096*256]  MFMA-shuffled
// (Xh and x2_np are GONE: score blocks self-stage x and compute norms.)
// Fallback (small ws): Wh in encodings region + separate k_onehot.

static __device__ __forceinline__ unsigned short f2bf(float f) {
    unsigned int u = __float_as_uint(f);
    u = (u + 0x7fffu + ((u >> 16) & 1u)) >> 16;   // RTN-even
    return (unsigned short)u;
}

// ---------------- numpy-pairwise fp32 row norms (r3-proven bit-exact) ------
__device__ __forceinline__ float pw128_sq(const float4* a4) {
#pragma clang fp contract(off)
    float4 v0 = a4[0], v1 = a4[1];
    float r0 = v0.x * v0.x, r1 = v0.y * v0.y, r2 = v0.z * v0.z, r3 = v0.w * v0.w;
    float r4 = v1.x * v1.x, r5 = v1.y * v1.y, r6 = v1.z * v1.z, r7 = v1.w * v1.w;
    #pragma unroll
    for (int i = 1; i < 16; ++i) {
        v0 = a4[2 * i]; v1 = a4[2 * i + 1];
        float s;
        s = v0.x * v0.x; r0 += s;
        s = v0.y * v0.y; r1 += s;
        s = v0.z * v0.z; r2 += s;
        s = v0.w * v0.w; r3 += s;
        s = v1.x * v1.x; r4 += s;
        s = v1.y * v1.y; r5 += s;
        s = v1.z * v1.z; r6 += s;
        s = v1.w * v1.w; r7 += s;
    }
    return ((r0 + r1) + (r2 + r3)) + ((r4 + r5) + (r6 + r7));
}

// ---- Wh-only prep: bf16 MFMA-shuffle + bit-exact row norms (r5-verified
// geometry, w branch only). 256 blocks, ~5us. The x side is self-staged
// inside k_score_mfma now.
__global__ __launch_bounds__(256) void k_prep_w(const float* __restrict__ w,
                                                unsigned short* __restrict__ Wh,
                                                float* __restrict__ e2_np) {
    const int T = blockIdx.x;
    const int t = threadIdx.x, lane = t & 63, g = t >> 6;
    #pragma unroll
    for (int cc = 0; cc < 2; ++cc) {
        int C = g * 2 + cc;
        int row = T * 16 + (lane & 15);
        int col = C * 32 + (lane >> 4) * 8;
        const float* s = w + (size_t)row * DIM + col;
        us8 h;
        #pragma unroll
        for (int j = 0; j < 8; ++j) h[j] = f2bf(s[j]);
        *(us8*)(Wh + ((size_t)(T * 8 + C) * 64 + lane) * 8) = h;
    }
    if (t < 16) {
        int row = T * 16 + t;
        const float4* a = (const float4*)(w + (size_t)row * DIM);
        float lo = pw128_sq(a);
        float hi = pw128_sq(a + 32);
        e2_np[row] = lo + hi;
    }
}

// ---- fused MFMA scoring: r1-proven structure VERBATIM (32 tok/block, lb4,
// drip-in-loop one-hot zero-fill, branchy top-2, np-exact refine), with one
// change: X self-staging. Each block reads its 32 raw fp32 x rows (32 KB,
// coalesced), converts bf16 in-register, ds_writes the MFMA layout into Abuf
// (index-identical to k_shuf1 + global_load_lds composition), and computes
// the 32 row norms bit-exactly into shared x2s. Removes the 32 MB Xh HBM
// round-trip and 3 of 4 prep dispatches. lb stays (256,4): r6 showed
// tightening the VGPR cap (lb5) shortens load-hoisting and loses ~27us.
__global__ __launch_bounds__(256, 4) void k_score_mfma(
        const float* __restrict__ x, const float* __restrict__ w,
        const float* __restrict__ e2_np,
        const unsigned short* __restrict__ Wh,
        float* __restrict__ out_idx, unsigned int* __restrict__ counts,
        float* enc,                       // nullable: fused one-hot
        float* __restrict__ outq, float* __restrict__ loss_acc) {
    __shared__ __align__(16) short Abuf[8192];   // [tile(2)][C(8)][lane][8] = 16 KB
    __shared__ float x2s[32];
    __shared__ float Tmax[4][32];
    __shared__ unsigned int ccnt[32];
    __shared__ int clist[32][16];
    __shared__ float Red_d[32 * 8];
    __shared__ int   Red_i[32 * 8];
    __shared__ float sred[4];

    const int t = threadIdx.x;
    const int wave = t >> 6, lane = t & 63;
    const int tok0 = blockIdx.x * 32;
    const int q = lane >> 4, c = lane & 15;

    // ---- self-stage A: thread t handles row t>>3, 32-float segment t&7 ----
    // Layout check: Abuf[((tile*8+C)*64+lane)*8+e] must equal
    // bf16(x[(tok0+tile*16+(lane&15))*256 + C*32 + (lane>>4)*8 + e]).
    // Here tile=row>>4, C=seg, lane=j*16+(row&15) => col=seg*32+j*8+e. OK.
    {
        int row = t >> 3, seg = t & 7;
        const float* xr = x + (size_t)(tok0 + row) * DIM + seg * 32;
        int base = ((row >> 4) * 8 + seg) * 64;
        int l16 = row & 15;
        #pragma unroll
        for (int j = 0; j < 4; ++j) {
            float4 a = *(const float4*)(xr + j * 8);
            float4 b = *(const float4*)(xr + j * 8 + 4);
            us8 h;
            h[0] = f2bf(a.x); h[1] = f2bf(a.y); h[2] = f2bf(a.z); h[3] = f2bf(a.w);
            h[4] = f2bf(b.x); h[5] = f2bf(b.y); h[6] = f2bf(b.z); h[7] = f2bf(b.w);
            *(us8*)(Abuf + ((size_t)(base + j * 16 + l16)) * 8) = h;
        }
    }
    if (t < 32) {
        ccnt[t] = 0;
        // bit-exact np row norm on L1-hot row
        const float4* a = (const float4*)(x + (size_t)(tok0 + t) * DIM);
        float lo = pw128_sq(a);
        float hi = pw128_sq(a + 32);
        x2s[t] = lo + hi;
    }
    __syncthreads();

    f32x4* ez = enc ? (f32x4*)(enc + (size_t)tok0 * N_EMB) : (f32x4*)0;
    const f32x4 zf4 = {0.f, 0.f, 0.f, 0.f};

    // ---- single pass: per-token packed top-2; one-hot zero-fill drip-fed ----
    float vmax[8], v2[8];
    #pragma unroll
    for (int s = 0; s < 8; ++s) { vmax[s] = -3.4e38f; v2[s] = -3.4e38f; }
    for (int jt = 0; jt < N_EMB; jt += 256) {
        const int U0 = (jt >> 4) + wave * 4;
        f32x4 acc[2][4] = {};
        #pragma unroll
        for (int C = 0; C < 8; ++C) {
            bf16x8 ah[2], bh[4];
            #pragma unroll
            for (int m = 0; m < 2; ++m)
                ah[m] = *(const bf16x8*)(Abuf + (size_t)(m * 8 + C) * 512 + lane * 8);
            #pragma unroll
            for (int n = 0; n < 4; ++n)
                bh[n] = *(const bf16x8*)(Wh + (((size_t)(U0 + n) * 8 + C) * 64 + lane) * 8);
            #pragma unroll
            for (int m = 0; m < 2; ++m)
                #pragma unroll
                for (int n = 0; n < 4; ++n)
                    acc[m][n] = __builtin_amdgcn_mfma_f32_16x16x32_bf16(ah[m], bh[n], acc[m][n], 0, 0, 0);
        }
        // packed top-2 update: low 6 mantissa bits carry (jtTile, n)
        {
            unsigned int idb = ((unsigned int)jt >> 8) << 2;
            #pragma unroll
            for (int m = 0; m < 2; ++m)
                #pragma unroll
                for (int n = 0; n < 4; ++n)
                    #pragma unroll
                    for (int r = 0; r < 4; ++r) {
                        float p = __uint_as_float(
                            (__float_as_uint(acc[m][n][r]) & ~63u) | (idb + (unsigned)n));
                        int s = m * 4 + r;
                        if (p > vmax[s]) { v2[s] = vmax[s]; vmax[s] = p; }
                        else if (p > v2[s]) v2[s] = p;
                    }
        }
        if (ez) {   // 8 x 16B nt zero-stores per thread per jt = 512 KB/block total
            int base = (jt >> 8) * 8 * 256 + t;
            #pragma unroll
            for (int j = 0; j < 8; ++j)
                __builtin_nontemporal_store(zf4, ez + base + j * 256);
        }
    }
    // reduce over the 16 c-lanes of each q-group (keep per-thread vmax/v2!)
    float rmax[8];
    #pragma unroll
    for (int s = 0; s < 8; ++s) rmax[s] = vmax[s];
    #pragma unroll
    for (int off = 1; off < 16; off <<= 1)
        #pragma unroll
        for (int s = 0; s < 8; ++s)
            rmax[s] = fmaxf(rmax[s], __shfl_xor(rmax[s], off));
    if (c == 0) {
        #pragma unroll
        for (int m = 0; m < 2; ++m)
            #pragma unroll
            for (int r = 0; r < 4; ++r)
                Tmax[wave][m * 16 + q * 4 + r] = rmax[m * 4 + r];
    }
    __syncthreads();
    if (t < 32) {
        float mx = fmaxf(fmaxf(Tmax[0][t], Tmax[1][t]),
                         fmaxf(Tmax[2][t], Tmax[3][t]));
        Tmax[0][t] = mx - 1.5e-4f;     // threshold (r6/r7-proven margin)
    }
    __syncthreads();
    float thr[8];
    #pragma unroll
    for (int m = 0; m < 2; ++m)
        #pragma unroll
        for (int r = 0; r < 4; ++r)
            thr[m * 4 + r] = Tmax[0][m * 16 + q * 4 + r];

    // ---- candidate push from registers (no recompute pass) ----
    #pragma unroll
    for (int s = 0; s < 8; ++s) {
        int m = s >> 2, r = s & 3;
        int tokl = m * 16 + q * 4 + r;
        #pragma unroll
        for (int h = 0; h < 2; ++h) {
            float pv = h ? v2[s] : vmax[s];
            if (pv >= thr[s]) {
                unsigned int id = __float_as_uint(pv) & 63u;
                int code = ((int)(id >> 2) * 16 + wave * 4 + (int)(id & 3u)) * 16 + c;
                unsigned int p = atomicAdd(&ccnt[tokl], 1u);
                if (p < 16) clist[tokl][p] = code;
            }
        }
    }
    __syncthreads();

    // ---- np-fp32-exact refinement: 8 threads/token over the list ----
    {
        int token = t >> 3, slot = t & 7;
        int cnt = (int)ccnt[token]; if (cnt > 16) cnt = 16;
        float bd = 3.4e38f;
        int bi = 0x7fffffff;
        float x2 = x2s[token];
        const float4* xr = (const float4*)(x + (size_t)(tok0 + token) * DIM);
        for (int k = slot; k < cnt; k += 8) {
            int code = clist[token][k];
            const float4* wr = (const float4*)(w + (size_t)code * DIM);
            double dot = 0.0;
            for (int g = 0; g < 64; ++g) {
                float4 xv = xr[g];
                float4 wv = wr[g];
                dot += (double)xv.x * (double)wv.x;
                dot += (double)xv.y * (double)wv.y;
                dot += (double)xv.z * (double)wv.z;
                dot += (double)xv.w * (double)wv.w;
            }
            {
#pragma clang fp contract(off)
                float M  = (float)dot;          // BLAS sgemm entry (~2e-9)
                float S  = x2 + e2_np[code];    // np broadcast add (fp32)
                float dd = S - 2.0f * M;        // fp32 sub -> ulp bucket
                if (dd < bd || (dd == bd && code < bi)) { bd = dd; bi = code; }
            }
        }
        Red_d[token * 8 + slot] = bd;
        Red_i[token * 8 + slot] = bi;
    }
    __syncthreads();
    if (t < 32) {
        float fv = Red_d[t * 8];
        int   fi = Red_i[t * 8];
        #pragma unroll
        for (int k = 1; k < 8; ++k) {
            float v = Red_d[t * 8 + k];
            int  ii = Red_i[t * 8 + k];
            if (v < fv || (v == fv && ii < fi)) { fv = v; fi = ii; }
        }
        out_idx[tok0 + t] = (float)fi;
        atomicAdd(&counts[fi], 1u);
        ccnt[t] = (unsigned int)fi;   // publish for epilogue
    }
    __syncthreads();

    // ---- epilogue: 1.0f scatter + quantized gather + commitment loss ----
    {
        int token = t >> 3, slot = t & 7;
        int fi = (int)ccnt[token];
        // zero-stores for this row drained at the Tmax __syncthreads (vmcnt(0));
        // same-XCD L2 ordering makes this 1.0f land after them.
        if (enc && slot == 0)
            __builtin_nontemporal_store(1.0f, enc + (size_t)(tok0 + token) * N_EMB + fi);
        const f32x4* wr = (const f32x4*)(w + (size_t)fi * DIM);
        const f32x4* xr = (const f32x4*)(x + (size_t)(tok0 + token) * DIM);
        f32x4* oq = (f32x4*)(outq + (size_t)(tok0 + token) * DIM);
        float sse = 0.f;
        #pragma unroll
        for (int g0 = 0; g0 < 8; ++g0) {
            int g = slot * 8 + g0;
            f32x4 qv = wr[g];
            f32x4 xv = xr[g];
            __builtin_nontemporal_store(qv, oq + g);
            float dx = qv.x - xv.x, dy = qv.y - xv.y;
            float dz = qv.z - xv.z, dw = qv.w - xv.w;
            sse += dx * dx + dy * dy + dz * dz + dw * dw;
        }
        #pragma unroll
        for (int off = 32; off > 0; off >>= 1) sse += __shfl_down(sse, off, 64);
        if (lane == 0) sred[wave] = sse;
    }
    __syncthreads();
    if (t == 0)
        atomicAdd(loss_acc, sred[0] + sred[1] + sred[2] + sred[3]);
}

// ---------------- one-hot encodings (fallback path only) ----------------
__global__ __launch_bounds__(256) void k_onehot(const float* __restrict__ out_idx,
                                                float* __restrict__ enc) {
    int token = blockIdx.x;
    int idx = (int)out_idx[token];
    float4* row = (float4*)(enc + (size_t)token * N_EMB);
    #pragma unroll
    for (int p = 0; p < 4; ++p) {
        int g = threadIdx.x + 256 * p;
        float4 v = make_float4(0.f, 0.f, 0.f, 0.f);
        int d0 = g * 4;
        if (idx >= d0 && idx < d0 + 4) ((float*)&v)[idx - d0] = 1.0f;
        row[g] = v;
    }
}

// ---------------- perplexity + loss finalize ----------------
__global__ __launch_bounds__(256) void k_final(const unsigned int* __restrict__ counts,
                                               const float* __restrict__ loss_acc,
                                               float* __restrict__ out_perp,
                                               float* __restrict__ out_loss) {
    __shared__ float sred[4];
    int t = threadIdx.x;
    float h = 0.f;
    for (int k = t; k < N_EMB; k += 256) {
        float p = (float)counts[k] * (1.0f / N_TOK);
        h += p * logf(p + 1e-10f);
    }
    #pragma unroll
    for (int off = 32; off > 0; off >>= 1) h += __shfl_down(h, off, 64);
    if ((t & 63) == 0) sred[t >> 6] = h;
    __syncthreads();
    if (t == 0) {
        float s = sred[0] + sred[1] + sred[2] + sred[3];
        *out_perp = expf(-s);
        *out_loss = loss_acc[0] * 1.25f / 8388608.0f;
    }
}

extern "C" void kernel_launch(void* const* d_in, const int* in_sizes, int n_in,
                              void* d_out, int out_size, void* d_ws, size_t ws_size,
                              hipStream_t stream) {
    const float* x = (const float*)d_in[0];
    const float* w = (const float*)d_in[1];
    float* out  = (float*)d_out;
    float* out0 = out;                       // quantized_st [32768*256]
    float* out1 = out0 + 8388608;            // perplexity   [1]
    float* out2 = out1 + 1;                  // encodings    [32768*4096]
    float* out3 = out2 + 134217728;          // indices      [32768] (as float)
    float* out4 = out3 + 32768;              // loss         [1]

    unsigned int* counts = (unsigned int*)d_ws;
    float* loss_acc = (float*)((char*)d_ws + 16384);
    float* e2_np    = (float*)((char*)d_ws + 16896);

    // Primary: Wh in d_ws, enc zeroed by the r1-proven drip inside the score
    // jt-loop + 1.0f scatter. Fallback (small ws): Wh aliases out2 -> no
    // fused enc, full-row k_onehot after score.
    bool big_ws = ws_size >= (size_t)(20u * 1024u * 1024u);
    unsigned short* Wh;
    float* enc_arg;
    if (big_ws) {
        Wh = (unsigned short*)((char*)d_ws + 17u * 1024u * 1024u);   // 2 MB
        enc_arg = out2;
    } else {
        uintptr_t sb = ((uintptr_t)out2 + 255) & ~(uintptr_t)255;
        Wh = (unsigned short*)sb;
        enc_arg = nullptr;
    }

    hipMemsetAsync(d_ws, 0, 16640, stream);
    k_prep_w<<<N_EMB / 16, 256, 0, stream>>>(w, Wh, e2_np);
    k_score_mfma<<<N_TOK / 32, 256, 0, stream>>>(x, w, e2_np, Wh,
                                                 out3, counts, enc_arg,
                                                 out0, loss_acc);
    if (!big_ws)
        k_onehot<<<N_TOK, 256, 0, stream>>>(out3, out2);
    k_final<<<1, 256, 0, stream>>>(counts, loss_acc, out1, out4);
}